// Round 1
// baseline (23127.251 us; speedup 1.0000x reference)
//
#include <hip/hip_runtime.h>
#include <hip/hip_cooperative_groups.h>

#define BB 32
#define TT 512
#define INW 256
#define HH 1024
#define OUTW 256
// 3H = 3072

typedef __attribute__((ext_vector_type(8))) short short8;
typedef __attribute__((ext_vector_type(4))) float floatx4;

__device__ __forceinline__ unsigned short f2bf(float f) {
    unsigned int u = __float_as_uint(f);
    u = (u + 0x7fffu + ((u >> 16) & 1u)) >> 16;
    return (unsigned short)u;
}
__device__ __forceinline__ float bf2f(unsigned short h) {
    return __uint_as_float(((unsigned int)h) << 16);
}

__global__ void cast_f32_bf16(const float* __restrict__ src,
                              unsigned short* __restrict__ dst, int n) {
    int i = blockIdx.x * blockDim.x + threadIdx.x;
    int stride = gridDim.x * blockDim.x;
    for (; i < n; i += stride) dst[i] = f2bf(src[i]);
}

// C_bf16[M x 3072] = X_bf16[M x K] @ W_bf16[3072 x K]^T + bias_f32
// tile 64x64, BK=32, 4 waves in 2x2, each wave 32x32 (2x2 MFMA tiles)
template <int K>
__global__ __launch_bounds__(256) void gemm_gx(const unsigned short* __restrict__ X,
                                               const unsigned short* __restrict__ W,
                                               const float* __restrict__ bias,
                                               unsigned short* __restrict__ Cout) {
    __shared__ __align__(16) unsigned short As[64 * 40];
    __shared__ __align__(16) unsigned short Bs[64 * 40];
    int bid = blockIdx.x;
    int tn = bid % 48, tm = bid / 48;
    int tid = threadIdx.x;
    int lane = tid & 63, wv = tid >> 6;
    int wm = wv >> 1, wn = wv & 1;
    int l15 = lane & 15, q = lane >> 4;
    floatx4 acc[2][2] = {};
    int r = tid >> 2, kq = (tid & 3) * 8;
    const int NK = K / 32;
    for (int kk = 0; kk < NK; ++kk) {
        int k0 = kk * 32;
        *(short8*)&As[r * 40 + kq] = *(const short8*)&X[(size_t)(tm * 64 + r) * K + k0 + kq];
        *(short8*)&Bs[r * 40 + kq] = *(const short8*)&W[(size_t)(tn * 64 + r) * K + k0 + kq];
        __syncthreads();
        short8 a0 = *(const short8*)&As[(wm * 32 + l15) * 40 + q * 8];
        short8 a1 = *(const short8*)&As[(wm * 32 + 16 + l15) * 40 + q * 8];
        short8 b0 = *(const short8*)&Bs[(wn * 32 + l15) * 40 + q * 8];
        short8 b1 = *(const short8*)&Bs[(wn * 32 + 16 + l15) * 40 + q * 8];
        acc[0][0] = __builtin_amdgcn_mfma_f32_16x16x32_bf16(a0, b0, acc[0][0], 0, 0, 0);
        acc[0][1] = __builtin_amdgcn_mfma_f32_16x16x32_bf16(a0, b1, acc[0][1], 0, 0, 0);
        acc[1][0] = __builtin_amdgcn_mfma_f32_16x16x32_bf16(a1, b0, acc[1][0], 0, 0, 0);
        acc[1][1] = __builtin_amdgcn_mfma_f32_16x16x32_bf16(a1, b1, acc[1][1], 0, 0, 0);
        __syncthreads();
    }
    for (int mi = 0; mi < 2; ++mi)
        for (int ni = 0; ni < 2; ++ni) {
            int col = tn * 64 + wn * 32 + ni * 16 + l15;
            float bv = bias[col];
            int row0 = tm * 64 + wm * 32 + mi * 16 + q * 4;
            for (int rr = 0; rr < 4; ++rr) {
                Cout[(size_t)(row0 + rr) * 3072 + col] = f2bf(acc[mi][ni][rr] + bv);
            }
        }
}

// Persistent cooperative GRU recurrence. 64 blocks x 256 threads.
// Block owns j-slice [bid*16, bid*16+16); computes gh cols {j, 1024+j, 2048+j}.
// 4 waves k-split (256 each), LDS reduce, block-local gate combine, 1 grid sync/step.
__global__ __launch_bounds__(256) void gru_rec(const unsigned short* __restrict__ gx,
                                               const unsigned short* __restrict__ whh,
                                               const float* __restrict__ bhh,
                                               float* __restrict__ h32,
                                               unsigned short* __restrict__ h16,
                                               unsigned short* __restrict__ out0,
                                               float* __restrict__ hn_out) {
    __shared__ __align__(16) float red[4 * 6 * 64 * 4];
    cooperative_groups::grid_group grid = cooperative_groups::this_grid();
    const int bid = blockIdx.x;
    const int tid = threadIdx.x;
    const int lane = tid & 63, wv = tid >> 6;
    const int l15 = lane & 15, q = lane >> 4;
    const int j0 = bid * 16;

    // zero initial h buffers (buffer 0 of each)
    int g = bid * 256 + tid;  // 0..16383
    h32[g] = 0.f;
    h32[g + 16384] = 0.f;
    h16[g] = 0;
    h16[g + 16384] = 0;
    grid.sync();

    const int kbase = wv * 256;
    const unsigned short* wr0 = whh + (size_t)(j0 + l15) * HH;
    const unsigned short* wr1 = whh + (size_t)(1024 + j0 + l15) * HH;
    const unsigned short* wr2 = whh + (size_t)(2048 + j0 + l15) * HH;

    for (int t = 0; t < TT; ++t) {
        const float* hc32 = h32 + (t & 1) * (BB * HH);
        float* hn32 = h32 + ((t + 1) & 1) * (BB * HH);
        const unsigned short* hc16 = h16 + (t & 1) * (BB * HH);
        unsigned short* hn16 = h16 + ((t + 1) & 1) * (BB * HH);

        floatx4 acc[6] = {};  // tile = mi*3 + gate
#pragma unroll 4
        for (int s = 0; s < 8; ++s) {
            int k = kbase + s * 32 + q * 8;
            short8 a0 = *(const short8*)&hc16[(size_t)(l15)*HH + k];
            short8 a1 = *(const short8*)&hc16[(size_t)(16 + l15) * HH + k];
            short8 b0 = *(const short8*)&wr0[k];
            short8 b1 = *(const short8*)&wr1[k];
            short8 b2 = *(const short8*)&wr2[k];
            acc[0] = __builtin_amdgcn_mfma_f32_16x16x32_bf16(a0, b0, acc[0], 0, 0, 0);
            acc[1] = __builtin_amdgcn_mfma_f32_16x16x32_bf16(a0, b1, acc[1], 0, 0, 0);
            acc[2] = __builtin_amdgcn_mfma_f32_16x16x32_bf16(a0, b2, acc[2], 0, 0, 0);
            acc[3] = __builtin_amdgcn_mfma_f32_16x16x32_bf16(a1, b0, acc[3], 0, 0, 0);
            acc[4] = __builtin_amdgcn_mfma_f32_16x16x32_bf16(a1, b1, acc[4], 0, 0, 0);
            acc[5] = __builtin_amdgcn_mfma_f32_16x16x32_bf16(a1, b2, acc[5], 0, 0, 0);
        }
#pragma unroll
        for (int tl = 0; tl < 6; ++tl)
            *(floatx4*)&red[((wv * 6 + tl) * 64 + lane) * 4] = acc[tl];
        __syncthreads();

        // gate phase: 512 (b, jl) pairs, 2 per thread
        for (int p = tid; p < 512; p += 256) {
            int b = p & 31, jl = p >> 5;
            int rl = ((b & 15) >> 2) * 16 + jl;  // lane holding this (row,col)
            int reg = b & 3;
            int mi = b >> 4;
            float gr = 0.f, gz = 0.f, gn = 0.f;
#pragma unroll
            for (int w = 0; w < 4; ++w) {
                gr += red[((w * 6 + mi * 3 + 0) * 64 + rl) * 4 + reg];
                gz += red[((w * 6 + mi * 3 + 1) * 64 + rl) * 4 + reg];
                gn += red[((w * 6 + mi * 3 + 2) * 64 + rl) * 4 + reg];
            }
            int j = j0 + jl;
            gr += bhh[j];
            gz += bhh[1024 + j];
            gn += bhh[2048 + j];
            const unsigned short* gxr = gx + (size_t)(b * TT + t) * 3072;
            float xr = bf2f(gxr[j]);
            float xz = bf2f(gxr[1024 + j]);
            float xn = bf2f(gxr[2048 + j]);
            float rg = 1.f / (1.f + __expf(-(xr + gr)));
            float zg = 1.f / (1.f + __expf(-(xz + gz)));
            float ng = tanhf(xn + rg * gn);
            float hold = hc32[b * HH + j];
            float hnew = (1.f - zg) * ng + zg * hold;
            hn32[b * HH + j] = hnew;
            hn16[b * HH + j] = f2bf(hnew);
            if (out0) out0[(size_t)(b * TT + t) * HH + j] = f2bf(hnew);
            if (t == TT - 1) hn_out[b * HH + j] = hnew;
        }
        __syncthreads();
        __threadfence();
        grid.sync();
    }
}

__global__ void fc_out(const float* __restrict__ h1, const float* __restrict__ fcw,
                       const float* __restrict__ fcb, float* __restrict__ out) {
    int b = blockIdx.x, o = threadIdx.x;  // 32 x 256
    const float* hb = h1 + b * HH;
    const float* wr = fcw + o * HH;
    float acc = fcb[o];
    for (int k = 0; k < HH; k += 4) {
        acc += hb[k] * wr[k] + hb[k + 1] * wr[k + 1] + hb[k + 2] * wr[k + 2] +
               hb[k + 3] * wr[k + 3];
    }
    out[b * OUTW + o] = 1.f / (1.f + expf(-acc));
}

extern "C" void kernel_launch(void* const* d_in, const int* in_sizes, int n_in,
                              void* d_out, int out_size, void* d_ws, size_t ws_size,
                              hipStream_t stream) {
    (void)in_sizes; (void)n_in; (void)out_size; (void)ws_size;
    const float* input = (const float*)d_in[0];
    const float* w_ih0 = (const float*)d_in[1];
    const float* w_hh0 = (const float*)d_in[2];
    const float* b_ih0 = (const float*)d_in[3];
    const float* b_hh0 = (const float*)d_in[4];
    const float* w_ih1 = (const float*)d_in[5];
    const float* w_hh1 = (const float*)d_in[6];
    const float* b_ih1 = (const float*)d_in[7];
    const float* b_hh1 = (const float*)d_in[8];
    const float* fc_w = (const float*)d_in[9];
    const float* fc_b = (const float*)d_in[10];
    float* out = (float*)d_out;

    char* ws = (char*)d_ws;
    size_t off = 0;
    auto alloc = [&](size_t bytes) {
        void* p = ws + off;
        off += (bytes + 255) & ~(size_t)255;
        return p;
    };
    unsigned short* gx = (unsigned short*)alloc((size_t)16384 * 3072 * 2);
    unsigned short* out0 = (unsigned short*)alloc((size_t)16384 * 1024 * 2);
    float* h32 = (float*)alloc((size_t)2 * 32 * 1024 * 4);
    unsigned short* h16 = (unsigned short*)alloc((size_t)2 * 32 * 1024 * 2);
    unsigned short* in_bf = (unsigned short*)alloc((size_t)16384 * 256 * 2);
    unsigned short* wih0_bf = (unsigned short*)alloc((size_t)3072 * 256 * 2);
    unsigned short* whh0_bf = (unsigned short*)alloc((size_t)3072 * 1024 * 2);
    unsigned short* wih1_bf = (unsigned short*)alloc((size_t)3072 * 1024 * 2);
    unsigned short* whh1_bf = (unsigned short*)alloc((size_t)3072 * 1024 * 2);

    cast_f32_bf16<<<256, 256, 0, stream>>>(input, in_bf, 16384 * 256);
    cast_f32_bf16<<<64, 256, 0, stream>>>(w_ih0, wih0_bf, 3072 * 256);
    cast_f32_bf16<<<256, 256, 0, stream>>>(w_hh0, whh0_bf, 3072 * 1024);
    cast_f32_bf16<<<256, 256, 0, stream>>>(w_ih1, wih1_bf, 3072 * 1024);
    cast_f32_bf16<<<256, 256, 0, stream>>>(w_hh1, whh1_bf, 3072 * 1024);

    // ---- layer 0 ----
    gemm_gx<256><<<12288, 256, 0, stream>>>(in_bf, wih0_bf, b_ih0, gx);
    {
        const unsigned short* gx_a = gx;
        const unsigned short* whh_a = whh0_bf;
        const float* bhh_a = b_hh0;
        float* h32_a = h32;
        unsigned short* h16_a = h16;
        unsigned short* out0_a = out0;
        float* hn_a = out + 8192;  // h_n layer 0 section
        void* args[] = {&gx_a, &whh_a, &bhh_a, &h32_a, &h16_a, &out0_a, &hn_a};
        hipLaunchCooperativeKernel((const void*)gru_rec, dim3(64), dim3(256), args, 0,
                                   stream);
    }

    // ---- layer 1 ----
    gemm_gx<1024><<<12288, 256, 0, stream>>>(out0, wih1_bf, b_ih1, gx);
    {
        const unsigned short* gx_a = gx;
        const unsigned short* whh_a = whh1_bf;
        const float* bhh_a = b_hh1;
        float* h32_a = h32;
        unsigned short* h16_a = h16;
        unsigned short* out0_a = nullptr;
        float* hn_a = out + 8192 + 32768;  // h_n layer 1 section
        void* args[] = {&gx_a, &whh_a, &bhh_a, &h32_a, &h16_a, &out0_a, &hn_a};
        hipLaunchCooperativeKernel((const void*)gru_rec, dim3(64), dim3(256), args, 0,
                                   stream);
    }

    // ---- FC + sigmoid (final h of layer 1 is in h32 buffer 0) ----
    fc_out<<<32, 256, 0, stream>>>(h32, fc_w, fc_b, out);
}

// Round 2
// 11848.331 us; speedup vs baseline: 1.9519x; 1.9519x over previous
//
#include <hip/hip_runtime.h>
#include <hip/hip_cooperative_groups.h>

#define BB 32
#define TT 512
#define INW 256
#define HH 1024
#define OUTW 256
// 3H = 3072

typedef __attribute__((ext_vector_type(8))) short short8;
typedef __attribute__((ext_vector_type(4))) float floatx4;

__device__ __forceinline__ unsigned short f2bf(float f) {
    unsigned int u = __float_as_uint(f);
    u = (u + 0x7fffu + ((u >> 16) & 1u)) >> 16;
    return (unsigned short)u;
}
__device__ __forceinline__ float bf2f(unsigned short h) {
    return __uint_as_float(((unsigned int)h) << 16);
}

// Agent-scope (device-coherent, sc1) 16B load of an A-fragment from h16.
// Bypasses the non-coherent per-XCD L2 per-access, so we never need a
// cache-wide invalidate (which would evict the L2-resident weights).
__device__ __forceinline__ short8 load_h8(const unsigned short* p) {
    union { short8 s; unsigned int u[4]; } v;
    const unsigned int* up = (const unsigned int*)p;
    v.u[0] = __hip_atomic_load(up + 0, __ATOMIC_RELAXED, __HIP_MEMORY_SCOPE_AGENT);
    v.u[1] = __hip_atomic_load(up + 1, __ATOMIC_RELAXED, __HIP_MEMORY_SCOPE_AGENT);
    v.u[2] = __hip_atomic_load(up + 2, __ATOMIC_RELAXED, __HIP_MEMORY_SCOPE_AGENT);
    v.u[3] = __hip_atomic_load(up + 3, __ATOMIC_RELAXED, __HIP_MEMORY_SCOPE_AGENT);
    return v.s;
}

__global__ void cast_f32_bf16(const float* __restrict__ src,
                              unsigned short* __restrict__ dst, int n) {
    int i = blockIdx.x * blockDim.x + threadIdx.x;
    int stride = gridDim.x * blockDim.x;
    for (; i < n; i += stride) dst[i] = f2bf(src[i]);
}

// C_bf16[M x 3072] = X_bf16[M x K] @ W_bf16[3072 x K]^T + bias_f32
template <int K>
__global__ __launch_bounds__(256) void gemm_gx(const unsigned short* __restrict__ X,
                                               const unsigned short* __restrict__ W,
                                               const float* __restrict__ bias,
                                               unsigned short* __restrict__ Cout) {
    __shared__ __align__(16) unsigned short As[64 * 40];
    __shared__ __align__(16) unsigned short Bs[64 * 40];
    int bid = blockIdx.x;
    int tn = bid % 48, tm = bid / 48;
    int tid = threadIdx.x;
    int lane = tid & 63, wv = tid >> 6;
    int wm = wv >> 1, wn = wv & 1;
    int l15 = lane & 15, q = lane >> 4;
    floatx4 acc[2][2] = {};
    int r = tid >> 2, kq = (tid & 3) * 8;
    const int NK = K / 32;
    for (int kk = 0; kk < NK; ++kk) {
        int k0 = kk * 32;
        *(short8*)&As[r * 40 + kq] = *(const short8*)&X[(size_t)(tm * 64 + r) * K + k0 + kq];
        *(short8*)&Bs[r * 40 + kq] = *(const short8*)&W[(size_t)(tn * 64 + r) * K + k0 + kq];
        __syncthreads();
        short8 a0 = *(const short8*)&As[(wm * 32 + l15) * 40 + q * 8];
        short8 a1 = *(const short8*)&As[(wm * 32 + 16 + l15) * 40 + q * 8];
        short8 b0 = *(const short8*)&Bs[(wn * 32 + l15) * 40 + q * 8];
        short8 b1 = *(const short8*)&Bs[(wn * 32 + 16 + l15) * 40 + q * 8];
        acc[0][0] = __builtin_amdgcn_mfma_f32_16x16x32_bf16(a0, b0, acc[0][0], 0, 0, 0);
        acc[0][1] = __builtin_amdgcn_mfma_f32_16x16x32_bf16(a0, b1, acc[0][1], 0, 0, 0);
        acc[1][0] = __builtin_amdgcn_mfma_f32_16x16x32_bf16(a1, b0, acc[1][0], 0, 0, 0);
        acc[1][1] = __builtin_amdgcn_mfma_f32_16x16x32_bf16(a1, b1, acc[1][1], 0, 0, 0);
        __syncthreads();
    }
    for (int mi = 0; mi < 2; ++mi)
        for (int ni = 0; ni < 2; ++ni) {
            int col = tn * 64 + wn * 32 + ni * 16 + l15;
            float bv = bias[col];
            int row0 = tm * 64 + wm * 32 + mi * 16 + q * 4;
            for (int rr = 0; rr < 4; ++rr) {
                Cout[(size_t)(row0 + rr) * 3072 + col] = f2bf(acc[mi][ni][rr] + bv);
            }
        }
}

// Persistent GRU recurrence. 64 blocks x 256 threads. Hand-rolled monotone
// counter barrier (no L2 invalidate -> weights stay L2-resident all 512 steps).
// h (fp32) lives in thread-private registers; only bf16 h crosses blocks, via
// agent-scope (sc1) atomics. One barrier per step.
__global__ __launch_bounds__(256) void gru_rec(const unsigned short* __restrict__ gx,
                                               const unsigned short* __restrict__ whh,
                                               const float* __restrict__ bhh,
                                               unsigned short* __restrict__ h16,
                                               unsigned short* __restrict__ out0,
                                               float* __restrict__ hn_out,
                                               unsigned int* __restrict__ cnt) {
    __shared__ __align__(16) float red[4 * 6 * 64 * 4];
    const int bid = blockIdx.x;
    const int tid = threadIdx.x;
    const int lane = tid & 63, wv = tid >> 6;
    const int l15 = lane & 15, q = lane >> 4;
    const int j0 = bid * 16;
    const int kbase = wv * 256;
    const unsigned short* wr0 = whh + (size_t)(j0 + l15) * HH;
    const unsigned short* wr1 = whh + (size_t)(1024 + j0 + l15) * HH;
    const unsigned short* wr2 = whh + (size_t)(2048 + j0 + l15) * HH;

    // gate-phase ownership: thread -> (b, jl=2*jh) and (b, jl=2*jh+1), fixed
    // across steps so fp32 h stays in registers.
    const int b = tid & 31, jh = tid >> 5;
    const int mi = b >> 4, reg = b & 3;
    const int rbase = ((b & 15) >> 2) * 16 + 2 * jh;  // MFMA C-layout lane
    float hpriv[2] = {0.f, 0.f};
    const float bhr0 = bhh[j0 + 2 * jh], bhr1 = bhh[j0 + 2 * jh + 1];
    const float bhz0 = bhh[1024 + j0 + 2 * jh], bhz1 = bhh[1024 + j0 + 2 * jh + 1];
    const float bhn0 = bhh[2048 + j0 + 2 * jh], bhn1 = bhh[2048 + j0 + 2 * jh + 1];
    const unsigned short* gxb = gx + (size_t)b * TT * 3072 + j0 + 2 * jh;
    // prefetch gx gate values for t=0
    unsigned int pxr = *(const unsigned int*)(gxb);
    unsigned int pxz = *(const unsigned int*)(gxb + 1024);
    unsigned int pxn = *(const unsigned int*)(gxb + 2048);

    for (int t = 0; t < TT; ++t) {
        const unsigned short* hc16 = h16 + (t & 1) * (BB * HH);
        unsigned short* hn16 = h16 + ((t + 1) & 1) * (BB * HH);

        unsigned int cxr = pxr, cxz = pxz, cxn = pxn;
        if (t + 1 < TT) {  // prefetch next step's gx (independent of h)
            const unsigned short* g2 = gxb + (size_t)(t + 1) * 3072;
            pxr = *(const unsigned int*)(g2);
            pxz = *(const unsigned int*)(g2 + 1024);
            pxn = *(const unsigned int*)(g2 + 2048);
        }

        floatx4 acc[6] = {};  // tile = mi*3 + gate
#pragma unroll
        for (int s = 0; s < 8; ++s) {
            int k = kbase + s * 32 + q * 8;
            short8 a0 = load_h8(&hc16[(size_t)l15 * HH + k]);
            short8 a1 = load_h8(&hc16[(size_t)(16 + l15) * HH + k]);
            short8 b0 = *(const short8*)&wr0[k];
            short8 b1 = *(const short8*)&wr1[k];
            short8 b2 = *(const short8*)&wr2[k];
            acc[0] = __builtin_amdgcn_mfma_f32_16x16x32_bf16(a0, b0, acc[0], 0, 0, 0);
            acc[1] = __builtin_amdgcn_mfma_f32_16x16x32_bf16(a0, b1, acc[1], 0, 0, 0);
            acc[2] = __builtin_amdgcn_mfma_f32_16x16x32_bf16(a0, b2, acc[2], 0, 0, 0);
            acc[3] = __builtin_amdgcn_mfma_f32_16x16x32_bf16(a1, b0, acc[3], 0, 0, 0);
            acc[4] = __builtin_amdgcn_mfma_f32_16x16x32_bf16(a1, b1, acc[4], 0, 0, 0);
            acc[5] = __builtin_amdgcn_mfma_f32_16x16x32_bf16(a1, b2, acc[5], 0, 0, 0);
        }
#pragma unroll
        for (int tl = 0; tl < 6; ++tl)
            *(floatx4*)&red[((wv * 6 + tl) * 64 + lane) * 4] = acc[tl];
        __syncthreads();

        float hnew[2];
#pragma unroll
        for (int i = 0; i < 2; ++i) {
            int rl = rbase + i;
            float gr = 0.f, gz = 0.f, gn = 0.f;
#pragma unroll
            for (int w = 0; w < 4; ++w) {
                gr += red[((w * 6 + mi * 3 + 0) * 64 + rl) * 4 + reg];
                gz += red[((w * 6 + mi * 3 + 1) * 64 + rl) * 4 + reg];
                gn += red[((w * 6 + mi * 3 + 2) * 64 + rl) * 4 + reg];
            }
            gr += i ? bhr1 : bhr0;
            gz += i ? bhz1 : bhz0;
            gn += i ? bhn1 : bhn0;
            float xr = bf2f((unsigned short)(i ? (cxr >> 16) : (cxr & 0xffffu)));
            float xz = bf2f((unsigned short)(i ? (cxz >> 16) : (cxz & 0xffffu)));
            float xn = bf2f((unsigned short)(i ? (cxn >> 16) : (cxn & 0xffffu)));
            float rg = 1.f / (1.f + __expf(-(xr + gr)));
            float zg = 1.f / (1.f + __expf(-(xz + gz)));
            float ng = tanhf(xn + rg * gn);
            hnew[i] = (1.f - zg) * ng + zg * hpriv[i];
            hpriv[i] = hnew[i];
        }
        unsigned int hpack =
            (unsigned int)f2bf(hnew[0]) | ((unsigned int)f2bf(hnew[1]) << 16);
        int jj = b * HH + j0 + 2 * jh;
        __hip_atomic_store((unsigned int*)&hn16[jj], hpack, __ATOMIC_RELAXED,
                           __HIP_MEMORY_SCOPE_AGENT);
        if (out0)
            *(unsigned int*)&out0[(size_t)(b * TT + t) * HH + j0 + 2 * jh] = hpack;
        if (t == TT - 1) {
            hn_out[jj] = hnew[0];
            hn_out[jj + 1] = hnew[1];
        }

        // ---- barrier: release(waitcnt) -> block sync -> counter -> spin ----
        asm volatile("s_waitcnt vmcnt(0)" ::: "memory");
        __syncthreads();
        if (tid == 0) {
            __hip_atomic_fetch_add(cnt, 1u, __ATOMIC_RELAXED, __HIP_MEMORY_SCOPE_AGENT);
            unsigned int target = (unsigned int)(t + 1) * 64u;
            while (__hip_atomic_load(cnt, __ATOMIC_RELAXED, __HIP_MEMORY_SCOPE_AGENT) <
                   target)
                __builtin_amdgcn_s_sleep(1);
        }
        __syncthreads();
    }
}

__global__ void fc_out(const float* __restrict__ h1, const float* __restrict__ fcw,
                       const float* __restrict__ fcb, float* __restrict__ out) {
    int b = blockIdx.x, o = threadIdx.x;  // 32 x 256
    const float* hb = h1 + b * HH;
    const float* wr = fcw + o * HH;
    float acc = fcb[o];
    for (int k = 0; k < HH; k += 4) {
        acc += hb[k] * wr[k] + hb[k + 1] * wr[k + 1] + hb[k + 2] * wr[k + 2] +
               hb[k + 3] * wr[k + 3];
    }
    out[b * OUTW + o] = 1.f / (1.f + expf(-acc));
}

extern "C" void kernel_launch(void* const* d_in, const int* in_sizes, int n_in,
                              void* d_out, int out_size, void* d_ws, size_t ws_size,
                              hipStream_t stream) {
    (void)in_sizes; (void)n_in; (void)out_size; (void)ws_size;
    const float* input = (const float*)d_in[0];
    const float* w_ih0 = (const float*)d_in[1];
    const float* w_hh0 = (const float*)d_in[2];
    const float* b_ih0 = (const float*)d_in[3];
    const float* b_hh0 = (const float*)d_in[4];
    const float* w_ih1 = (const float*)d_in[5];
    const float* w_hh1 = (const float*)d_in[6];
    const float* b_ih1 = (const float*)d_in[7];
    const float* b_hh1 = (const float*)d_in[8];
    const float* fc_w = (const float*)d_in[9];
    const float* fc_b = (const float*)d_in[10];
    float* out = (float*)d_out;

    char* ws = (char*)d_ws;
    size_t off = 0;
    auto alloc = [&](size_t bytes) {
        void* p = ws + off;
        off += (bytes + 255) & ~(size_t)255;
        return p;
    };
    // cnt and h16 contiguous so one memset clears both
    unsigned int* cnt = (unsigned int*)alloc(256);
    unsigned short* h16 = (unsigned short*)alloc((size_t)2 * BB * HH * 2);  // 128 KB
    unsigned short* gx = (unsigned short*)alloc((size_t)16384 * 3072 * 2);
    unsigned short* out0 = (unsigned short*)alloc((size_t)16384 * 1024 * 2);
    unsigned short* in_bf = (unsigned short*)alloc((size_t)16384 * 256 * 2);
    unsigned short* wih0_bf = (unsigned short*)alloc((size_t)3072 * 256 * 2);
    unsigned short* whh0_bf = (unsigned short*)alloc((size_t)3072 * 1024 * 2);
    unsigned short* wih1_bf = (unsigned short*)alloc((size_t)3072 * 1024 * 2);
    unsigned short* whh1_bf = (unsigned short*)alloc((size_t)3072 * 1024 * 2);

    cast_f32_bf16<<<256, 256, 0, stream>>>(input, in_bf, 16384 * 256);
    cast_f32_bf16<<<64, 256, 0, stream>>>(w_ih0, wih0_bf, 3072 * 256);
    cast_f32_bf16<<<256, 256, 0, stream>>>(w_hh0, whh0_bf, 3072 * 1024);
    cast_f32_bf16<<<256, 256, 0, stream>>>(w_ih1, wih1_bf, 3072 * 1024);
    cast_f32_bf16<<<256, 256, 0, stream>>>(w_hh1, whh1_bf, 3072 * 1024);

    // zero barrier counters + h16 double buffer (0xAA-poisoned otherwise)
    hipMemsetAsync(cnt, 0, 256 + (size_t)2 * BB * HH * 2, stream);

    // ---- layer 0 ----
    gemm_gx<256><<<12288, 256, 0, stream>>>(in_bf, wih0_bf, b_ih0, gx);
    {
        const unsigned short* gx_a = gx;
        const unsigned short* whh_a = whh0_bf;
        const float* bhh_a = b_hh0;
        unsigned short* h16_a = h16;
        unsigned short* out0_a = out0;
        float* hn_a = out + 8192;  // h_n layer 0
        unsigned int* cnt_a = cnt;
        void* args[] = {&gx_a, &whh_a, &bhh_a, &h16_a, &out0_a, &hn_a, &cnt_a};
        hipLaunchCooperativeKernel((const void*)gru_rec, dim3(64), dim3(256), args, 0,
                                   stream);
    }

    // re-zero h16 for layer 1 (layer-1 counter at cnt+32 untouched by layer 0)
    hipMemsetAsync(h16, 0, (size_t)2 * BB * HH * 2, stream);

    // ---- layer 1 ----
    gemm_gx<1024><<<12288, 256, 0, stream>>>(out0, wih1_bf, b_ih1, gx);
    {
        const unsigned short* gx_a = gx;
        const unsigned short* whh_a = whh1_bf;
        const float* bhh_a = b_hh1;
        unsigned short* h16_a = h16;
        unsigned short* out0_a = nullptr;
        float* hn_a = out + 8192 + 32768;  // h_n layer 1
        unsigned int* cnt_a = cnt + 32;    // separate cache line
        void* args[] = {&gx_a, &whh_a, &bhh_a, &h16_a, &out0_a, &hn_a, &cnt_a};
        hipLaunchCooperativeKernel((const void*)gru_rec, dim3(64), dim3(256), args, 0,
                                   stream);
    }

    // ---- FC + sigmoid on h_last of layer 1 ----
    fc_out<<<32, 256, 0, stream>>>(out + 8192 + 32768, fc_w, fc_b, out);
}

// Round 3
// 10586.083 us; speedup vs baseline: 2.1847x; 1.1192x over previous
//
#include <hip/hip_runtime.h>

#define BB 32
#define TT 512
#define INW 256
#define HH 1024
#define OUTW 256
// 3H = 3072

typedef __attribute__((ext_vector_type(8))) short short8;
typedef __attribute__((ext_vector_type(4))) float floatx4;

__device__ __forceinline__ unsigned short f2bf(float f) {
    unsigned int u = __float_as_uint(f);
    u = (u + 0x7fffu + ((u >> 16) & 1u)) >> 16;
    return (unsigned short)u;
}
__device__ __forceinline__ float bf2f(unsigned short h) {
    return __uint_as_float(((unsigned int)h) << 16);
}

// Agent-scope 16B load from h16: bypasses (stale) L1/L2 per-access, so no
// cache-wide invalidate is ever needed -> weights stay L2-resident.
__device__ __forceinline__ short8 load_h8(const unsigned short* p) {
    union { short8 s; unsigned int u[4]; } v;
    const unsigned int* up = (const unsigned int*)p;
    v.u[0] = __hip_atomic_load(up + 0, __ATOMIC_RELAXED, __HIP_MEMORY_SCOPE_AGENT);
    v.u[1] = __hip_atomic_load(up + 1, __ATOMIC_RELAXED, __HIP_MEMORY_SCOPE_AGENT);
    v.u[2] = __hip_atomic_load(up + 2, __ATOMIC_RELAXED, __HIP_MEMORY_SCOPE_AGENT);
    v.u[3] = __hip_atomic_load(up + 3, __ATOMIC_RELAXED, __HIP_MEMORY_SCOPE_AGENT);
    return v.s;
}

__global__ void cast_f32_bf16(const float* __restrict__ src,
                              unsigned short* __restrict__ dst, int n) {
    int i = blockIdx.x * blockDim.x + threadIdx.x;
    int stride = gridDim.x * blockDim.x;
    for (; i < n; i += stride) dst[i] = f2bf(src[i]);
}

// C_bf16[M x 3072] = X_bf16[M x K] @ W_bf16[3072 x K]^T + bias_f32
template <int K>
__global__ __launch_bounds__(256) void gemm_gx(const unsigned short* __restrict__ X,
                                               const unsigned short* __restrict__ W,
                                               const float* __restrict__ bias,
                                               unsigned short* __restrict__ Cout) {
    __shared__ __align__(16) unsigned short As[64 * 40];
    __shared__ __align__(16) unsigned short Bs[64 * 40];
    int bid = blockIdx.x;
    int tn = bid % 48, tm = bid / 48;
    int tid = threadIdx.x;
    int lane = tid & 63, wv = tid >> 6;
    int wm = wv >> 1, wn = wv & 1;
    int l15 = lane & 15, q = lane >> 4;
    floatx4 acc[2][2] = {};
    int r = tid >> 2, kq = (tid & 3) * 8;
    const int NK = K / 32;
    for (int kk = 0; kk < NK; ++kk) {
        int k0 = kk * 32;
        *(short8*)&As[r * 40 + kq] = *(const short8*)&X[(size_t)(tm * 64 + r) * K + k0 + kq];
        *(short8*)&Bs[r * 40 + kq] = *(const short8*)&W[(size_t)(tn * 64 + r) * K + k0 + kq];
        __syncthreads();
        short8 a0 = *(const short8*)&As[(wm * 32 + l15) * 40 + q * 8];
        short8 a1 = *(const short8*)&As[(wm * 32 + 16 + l15) * 40 + q * 8];
        short8 b0 = *(const short8*)&Bs[(wn * 32 + l15) * 40 + q * 8];
        short8 b1 = *(const short8*)&Bs[(wn * 32 + 16 + l15) * 40 + q * 8];
        acc[0][0] = __builtin_amdgcn_mfma_f32_16x16x32_bf16(a0, b0, acc[0][0], 0, 0, 0);
        acc[0][1] = __builtin_amdgcn_mfma_f32_16x16x32_bf16(a0, b1, acc[0][1], 0, 0, 0);
        acc[1][0] = __builtin_amdgcn_mfma_f32_16x16x32_bf16(a1, b0, acc[1][0], 0, 0, 0);
        acc[1][1] = __builtin_amdgcn_mfma_f32_16x16x32_bf16(a1, b1, acc[1][1], 0, 0, 0);
        __syncthreads();
    }
    for (int mi = 0; mi < 2; ++mi)
        for (int ni = 0; ni < 2; ++ni) {
            int col = tn * 64 + wn * 32 + ni * 16 + l15;
            float bv = bias[col];
            int row0 = tm * 64 + wm * 32 + mi * 16 + q * 4;
            for (int rr = 0; rr < 4; ++rr) {
                Cout[(size_t)(row0 + rr) * 3072 + col] = f2bf(acc[mi][ni][rr] + bv);
            }
        }
}

// Persistent GRU recurrence, 64 blocks x 256 threads.
// Flag-based step barrier: producer h-store(sc1) -> vmcnt(0) -> syncthreads ->
// flags[bid]=t+1 (relaxed agent). Consumer: each wave loads all 64 flags in one
// instruction and __all-checks. No RMW serialization, no L2 invalidates.
// Protocol safety: block writes buffer t&1 at step t+1 only after all flags
// >= t+1, which each block sets only AFTER its step-t reads of that buffer.
__global__ __launch_bounds__(256) void gru_rec(const unsigned short* __restrict__ gx,
                                               const unsigned short* __restrict__ whh,
                                               const float* __restrict__ bhh,
                                               unsigned short* __restrict__ h16,
                                               unsigned short* __restrict__ out0,
                                               float* __restrict__ hn_out,
                                               unsigned int* __restrict__ flags) {
    __shared__ __align__(16) float red[4 * 6 * 64 * 4];
    const int bid = blockIdx.x;
    const int tid = threadIdx.x;
    const int lane = tid & 63, wv = tid >> 6;
    const int l15 = lane & 15, q = lane >> 4;
    const int j0 = bid * 16;
    const int kbase = wv * 256;
    const unsigned short* wr0 = whh + (size_t)(j0 + l15) * HH;
    const unsigned short* wr1 = whh + (size_t)(1024 + j0 + l15) * HH;
    const unsigned short* wr2 = whh + (size_t)(2048 + j0 + l15) * HH;

    // gate-phase ownership: thread -> (b, 2*jh) and (b, 2*jh+1), fixed across
    // steps so fp32 h lives in registers.
    const int b = tid & 31, jh = tid >> 5;
    const int mi = b >> 4, reg = b & 3;
    const int rbase = ((b & 15) >> 2) * 16 + 2 * jh;  // MFMA C-layout lane
    float hpriv[2] = {0.f, 0.f};
    const float bhr0 = bhh[j0 + 2 * jh], bhr1 = bhh[j0 + 2 * jh + 1];
    const float bhz0 = bhh[1024 + j0 + 2 * jh], bhz1 = bhh[1024 + j0 + 2 * jh + 1];
    const float bhn0 = bhh[2048 + j0 + 2 * jh], bhn1 = bhh[2048 + j0 + 2 * jh + 1];
    const unsigned short* gxb = gx + (size_t)b * TT * 3072 + j0 + 2 * jh;
    unsigned int pxr = *(const unsigned int*)(gxb);
    unsigned int pxz = *(const unsigned int*)(gxb + 1024);
    unsigned int pxn = *(const unsigned int*)(gxb + 2048);

    for (int t = 0; t < TT; ++t) {
        // ---- wait for h(t) from all blocks: one flag-vector load per wave
        if (t > 0) {
            unsigned int target = (unsigned int)t;
            while (true) {
                unsigned int v = __hip_atomic_load(flags + lane, __ATOMIC_RELAXED,
                                                   __HIP_MEMORY_SCOPE_AGENT);
                if (__all((int)(v >= target))) break;
                __builtin_amdgcn_s_sleep(2);
            }
        }
        const unsigned short* hc16 = h16 + (t & 1) * (BB * HH);
        unsigned short* hn16 = h16 + ((t + 1) & 1) * (BB * HH);
        unsigned int cxr = pxr, cxz = pxz, cxn = pxn;

        floatx4 acc[6] = {};  // tile = mi*3 + gate
#pragma unroll
        for (int s = 0; s < 8; ++s) {
            int k = kbase + s * 32 + q * 8;
            short8 a0 = load_h8(&hc16[(size_t)l15 * HH + k]);
            short8 a1 = load_h8(&hc16[(size_t)(16 + l15) * HH + k]);
            short8 b0 = *(const short8*)&wr0[k];
            short8 b1 = *(const short8*)&wr1[k];
            short8 b2 = *(const short8*)&wr2[k];
            acc[0] = __builtin_amdgcn_mfma_f32_16x16x32_bf16(a0, b0, acc[0], 0, 0, 0);
            acc[1] = __builtin_amdgcn_mfma_f32_16x16x32_bf16(a0, b1, acc[1], 0, 0, 0);
            acc[2] = __builtin_amdgcn_mfma_f32_16x16x32_bf16(a0, b2, acc[2], 0, 0, 0);
            acc[3] = __builtin_amdgcn_mfma_f32_16x16x32_bf16(a1, b0, acc[3], 0, 0, 0);
            acc[4] = __builtin_amdgcn_mfma_f32_16x16x32_bf16(a1, b1, acc[4], 0, 0, 0);
            acc[5] = __builtin_amdgcn_mfma_f32_16x16x32_bf16(a1, b2, acc[5], 0, 0, 0);
        }
#pragma unroll
        for (int tl = 0; tl < 6; ++tl)
            *(floatx4*)&red[((wv * 6 + tl) * 64 + lane) * 4] = acc[tl];
        __syncthreads();

        float hnew[2];
#pragma unroll
        for (int i = 0; i < 2; ++i) {
            int rl = rbase + i;
            float gr = 0.f, gz = 0.f, gn = 0.f;
#pragma unroll
            for (int w = 0; w < 4; ++w) {
                gr += red[((w * 6 + mi * 3 + 0) * 64 + rl) * 4 + reg];
                gz += red[((w * 6 + mi * 3 + 1) * 64 + rl) * 4 + reg];
                gn += red[((w * 6 + mi * 3 + 2) * 64 + rl) * 4 + reg];
            }
            gr += i ? bhr1 : bhr0;
            gz += i ? bhz1 : bhz0;
            gn += i ? bhn1 : bhn0;
            float xr = bf2f((unsigned short)(i ? (cxr >> 16) : (cxr & 0xffffu)));
            float xz = bf2f((unsigned short)(i ? (cxz >> 16) : (cxz & 0xffffu)));
            float xn = bf2f((unsigned short)(i ? (cxn >> 16) : (cxn & 0xffffu)));
            float rg = 1.f / (1.f + __expf(-(xr + gr)));
            float zg = 1.f / (1.f + __expf(-(xz + gz)));
            float ng = tanhf(xn + rg * gn);
            hnew[i] = (1.f - zg) * ng + zg * hpriv[i];
            hpriv[i] = hnew[i];
        }
        unsigned int hpack =
            (unsigned int)f2bf(hnew[0]) | ((unsigned int)f2bf(hnew[1]) << 16);
        int jj = b * HH + j0 + 2 * jh;
        // release: only the h16 store is on the critical path
        __hip_atomic_store((unsigned int*)&hn16[jj], hpack, __ATOMIC_RELAXED,
                           __HIP_MEMORY_SCOPE_AGENT);
        asm volatile("s_waitcnt vmcnt(0)" ::: "memory");
        __syncthreads();
        if (tid == 0)
            __hip_atomic_store(flags + bid, (unsigned int)(t + 1), __ATOMIC_RELAXED,
                               __HIP_MEMORY_SCOPE_AGENT);
        // off-critical-path traffic
        if (out0)
            *(unsigned int*)&out0[(size_t)(b * TT + t) * HH + j0 + 2 * jh] = hpack;
        if (t == TT - 1) {
            hn_out[jj] = hnew[0];
            hn_out[jj + 1] = hnew[1];
        }
        if (t + 1 < TT) {
            const unsigned short* g2 = gxb + (size_t)(t + 1) * 3072;
            pxr = *(const unsigned int*)(g2);
            pxz = *(const unsigned int*)(g2 + 1024);
            pxn = *(const unsigned int*)(g2 + 2048);
        }
    }
}

__global__ void fc_out(const float* __restrict__ h1, const float* __restrict__ fcw,
                       const float* __restrict__ fcb, float* __restrict__ out) {
    int b = blockIdx.x, o = threadIdx.x;  // 32 x 256
    const float* hb = h1 + b * HH;
    const float* wr = fcw + o * HH;
    float acc = fcb[o];
    for (int k = 0; k < HH; k += 4) {
        acc += hb[k] * wr[k] + hb[k + 1] * wr[k + 1] + hb[k + 2] * wr[k + 2] +
               hb[k + 3] * wr[k + 3];
    }
    out[b * OUTW + o] = 1.f / (1.f + expf(-acc));
}

extern "C" void kernel_launch(void* const* d_in, const int* in_sizes, int n_in,
                              void* d_out, int out_size, void* d_ws, size_t ws_size,
                              hipStream_t stream) {
    (void)in_sizes; (void)n_in; (void)out_size; (void)ws_size;
    const float* input = (const float*)d_in[0];
    const float* w_ih0 = (const float*)d_in[1];
    const float* w_hh0 = (const float*)d_in[2];
    const float* b_ih0 = (const float*)d_in[3];
    const float* b_hh0 = (const float*)d_in[4];
    const float* w_ih1 = (const float*)d_in[5];
    const float* w_hh1 = (const float*)d_in[6];
    const float* b_ih1 = (const float*)d_in[7];
    const float* b_hh1 = (const float*)d_in[8];
    const float* fc_w = (const float*)d_in[9];
    const float* fc_b = (const float*)d_in[10];
    float* out = (float*)d_out;

    char* ws = (char*)d_ws;
    size_t off = 0;
    auto alloc = [&](size_t bytes) {
        void* p = ws + off;
        off += (bytes + 255) & ~(size_t)255;
        return p;
    };
    // flags (2 layers x 64 dwords, 256B apart) + h16 contiguous -> one memset
    unsigned int* flags = (unsigned int*)alloc(512);
    unsigned short* h16 = (unsigned short*)alloc((size_t)2 * BB * HH * 2);  // 128 KB
    unsigned short* gx = (unsigned short*)alloc((size_t)16384 * 3072 * 2);
    unsigned short* out0 = (unsigned short*)alloc((size_t)16384 * 1024 * 2);
    unsigned short* in_bf = (unsigned short*)alloc((size_t)16384 * 256 * 2);
    unsigned short* wih0_bf = (unsigned short*)alloc((size_t)3072 * 256 * 2);
    unsigned short* whh0_bf = (unsigned short*)alloc((size_t)3072 * 1024 * 2);
    unsigned short* wih1_bf = (unsigned short*)alloc((size_t)3072 * 1024 * 2);
    unsigned short* whh1_bf = (unsigned short*)alloc((size_t)3072 * 1024 * 2);

    cast_f32_bf16<<<256, 256, 0, stream>>>(input, in_bf, 16384 * 256);
    cast_f32_bf16<<<64, 256, 0, stream>>>(w_ih0, wih0_bf, 3072 * 256);
    cast_f32_bf16<<<256, 256, 0, stream>>>(w_hh0, whh0_bf, 3072 * 1024);
    cast_f32_bf16<<<256, 256, 0, stream>>>(w_ih1, wih1_bf, 3072 * 1024);
    cast_f32_bf16<<<256, 256, 0, stream>>>(w_hh1, whh1_bf, 3072 * 1024);

    hipMemsetAsync(flags, 0, 512 + (size_t)2 * BB * HH * 2, stream);

    // ---- layer 0 ----
    gemm_gx<256><<<12288, 256, 0, stream>>>(in_bf, wih0_bf, b_ih0, gx);
    gru_rec<<<64, 256, 0, stream>>>(gx, whh0_bf, b_hh0, h16, out0, out + 8192, flags);

    // re-zero h16 for layer 1 (layer-1 flags at +64 dwords untouched)
    hipMemsetAsync(h16, 0, (size_t)2 * BB * HH * 2, stream);

    // ---- layer 1 ----
    gemm_gx<1024><<<12288, 256, 0, stream>>>(out0, wih1_bf, b_ih1, gx);
    gru_rec<<<64, 256, 0, stream>>>(gx, whh1_bf, b_hh1, h16, (unsigned short*)nullptr,
                                    out + 8192 + 32768, flags + 64);

    // ---- FC + sigmoid on h_last of layer 1 ----
    fc_out<<<32, 256, 0, stream>>>(out + 8192 + 32768, fc_w, fc_b, out);
}